// Round 10
// baseline (523.269 us; speedup 1.0000x reference)
//
#include <hip/hip_runtime.h>

// Problem constants (N=2048, L=512, K=16, DROP=2, DIM=1024)
#define NDIM 2048
#define LLEV 512
#define KDIM 16
#define HALF 1024

typedef __attribute__((ext_vector_type(8))) short bf16x8;   // 8 bf16 = 4 VGPRs
typedef __attribute__((ext_vector_type(4))) float f32x4;
typedef __attribute__((ext_vector_type(16))) float f32x16;  // 32x32 MFMA acc

// ---------------------------------------------------------------------------
// bf16 split helpers: x ~= hi + lo, each RNE bf16 (~16-17 mantissa bits total)
// ---------------------------------------------------------------------------
__device__ inline unsigned short f2bf(float x) {
    unsigned u = __float_as_uint(x);
    u += 0x7fffu + ((u >> 16) & 1u);
    return (unsigned short)(u >> 16);
}
__device__ inline float bf2f(unsigned short b) {
    return __uint_as_float(((unsigned)b) << 16);
}
__device__ inline void split2(float x, unsigned short& h, unsigned short& l) {
    h = f2bf(x);
    l = f2bf(x - bf2f(h));
}

__device__ inline void gl2lds16(const void* g, void* l) {
    __builtin_amdgcn_global_load_lds(
        (const __attribute__((address_space(1))) void*)g,
        (__attribute__((address_space(3))) void*)l, 16, 0, 0);
}

// ---------------------------------------------------------------------------
// compose_kernel: pairwise level composition (validated R4/R5).
// 512 levels of 16 rows -> 256 composites of 32 rows.
// ---------------------------------------------------------------------------
__global__ __launch_bounds__(64) void compose_kernel(const float* __restrict__ O,
                                                     const int* __restrict__ idx,
                                                     int* __restrict__ Sarr,
                                                     float* __restrict__ Warr)
{
    __shared__ int s_S[32];
    __shared__ int s_pos[32];
    __shared__ float s_W[32][33];
    const int t = blockIdx.x;
    const int lane = threadIdx.x;
    const int* a = idx + (2 * t) * 16;
    const int* b = idx + (2 * t + 1) * 16;

    if (lane == 0) {
        int na = 0, i = 0, j = 0;
        while (i < 16 || j < 16) {
            int va = (i < 16) ? a[i] : 0x7fffffff;
            int vb = (j < 16) ? b[j] : 0x7fffffff;
            int v = va < vb ? va : vb;
            if (va == v) i++;
            if (vb == v) j++;
            s_S[na++] = v;
        }
        const int nm = na;
        int r = 0, p = 0;
        while (na < 32) {
            while (p < nm && s_S[p] < r) p++;
            if (p < nm && s_S[p] == r) { r++; continue; }
            s_S[na++] = r++;
        }
    }
    __syncthreads();
    if (lane < 32) {
        const int v = (lane < 16) ? a[lane] : b[lane - 16];
        int pp = 0;
        #pragma unroll
        for (int q = 0; q < 32; ++q) if (s_S[q] == v) pp = q;
        s_pos[lane] = pp;
        #pragma unroll
        for (int c = 0; c < 33; ++c) s_W[lane][c] = 0.f;
        s_W[lane][lane] = 1.f;
    }
    __syncthreads();
    const int j  = lane >> 2;
    const int cg = (lane & 3) * 8;
    #pragma unroll
    for (int step = 0; step < 2; ++step) {
        const float* Om = O + (size_t)(2 * t + step) * 256;
        float acc[8] = {};
        for (int k = 0; k < 16; ++k) {
            const float o = Om[j * 16 + k];
            const int p = s_pos[step * 16 + k];
            #pragma unroll
            for (int c = 0; c < 8; ++c) acc[c] += o * s_W[p][cg + c];
        }
        __syncthreads();
        const int pj = s_pos[step * 16 + j];
        #pragma unroll
        for (int c = 0; c < 8; ++c) s_W[pj][cg + c] = acc[c];
        __syncthreads();
    }
    if (lane < 32) Sarr[t * 32 + lane] = s_S[lane];
    {
        const int r = lane >> 1, h0 = (lane & 1) * 16;
        float* wp = Warr + (size_t)t * 1024 + r * 32 + h0;
        #pragma unroll
        for (int c = 0; c < 16; ++c) wp[c] = s_W[r][h0 + c];
    }
}

// ---------------------------------------------------------------------------
// scan3_fused: blocks 0..511 run the proven scan3 (latency-bound, chain of
// 256 steps); blocks 512+ run conv_hl(A) work in the scan's shadow.
// ---------------------------------------------------------------------------
__global__ __launch_bounds__(64) void scan3_fused(const float* __restrict__ Warr,
                                                  const int* __restrict__ Sarr,
                                                  float* __restrict__ right,
                                                  const float* __restrict__ Asrc,
                                                  unsigned short* __restrict__ Ahd,
                                                  unsigned short* __restrict__ Ald)
{
    __shared__ float slab[NDIM * 4];
    const int lane = threadIdx.x;

    if (blockIdx.x >= 512) {
        const long e = ((long)(blockIdx.x - 512) * 64 + lane) * 8;
        float4 v0 = *(const float4*)(Asrc + e);
        float4 v1 = *(const float4*)(Asrc + e + 4);
        ushort4 h0, l0, h1, l1;
        split2(v0.x, h0.x, l0.x); split2(v0.y, h0.y, l0.y);
        split2(v0.z, h0.z, l0.z); split2(v0.w, h0.w, l0.w);
        split2(v1.x, h1.x, l1.x); split2(v1.y, h1.y, l1.y);
        split2(v1.z, h1.z, l1.z); split2(v1.w, h1.w, l1.w);
        *(ushort4*)(Ahd + e)     = h0;
        *(ushort4*)(Ahd + e + 4) = h1;
        *(ushort4*)(Ald + e)     = l0;
        *(ushort4*)(Ald + e + 4) = l1;
        return;
    }

    const int c0 = blockIdx.x * 4;
    const int rr = lane & 31;
    const int ks = lane >> 5;

    for (int r = lane; r < NDIM; r += 64)
        *(float4*)&slab[r * 4] = make_float4(0.f, 0.f, 0.f, 0.f);
    if (lane < 4) slab[(c0 + lane) * 4 + lane] = 1.0f;

    int rows[16]; float cf[16]; int wrow;
    {
        const int4* sp = (const int4*)(Sarr + ks * 16);
        #pragma unroll
        for (int q = 0; q < 4; ++q) *(int4*)&rows[q * 4] = sp[q];
        const float4* wp = (const float4*)(Warr + rr * 32 + ks * 16);
        #pragma unroll
        for (int q = 0; q < 4; ++q) *(float4*)&cf[q * 4] = wp[q];
        wrow = Sarr[rr];
    }

    for (int t = 0; t < 256; ++t) {
        int cr[16]; float cc[16];
        const int wr = wrow;
        #pragma unroll
        for (int q = 0; q < 16; ++q) { cr[q] = rows[q]; cc[q] = cf[q]; }
        if (t + 1 < 256) {
            const int4* sp = (const int4*)(Sarr + (t + 1) * 32 + ks * 16);
            #pragma unroll
            for (int q = 0; q < 4; ++q) *(int4*)&rows[q * 4] = sp[q];
            const float4* wp = (const float4*)(Warr + (size_t)(t + 1) * 1024 + rr * 32 + ks * 16);
            #pragma unroll
            for (int q = 0; q < 4; ++q) *(float4*)&cf[q * 4] = wp[q];
            wrow = Sarr[(t + 1) * 32 + rr];
        }
        float4 acc = make_float4(0.f, 0.f, 0.f, 0.f);
        #pragma unroll
        for (int j = 0; j < 16; ++j) {
            float4 v = *(const float4*)&slab[cr[j] * 4];
            acc.x += cc[j] * v.x; acc.y += cc[j] * v.y;
            acc.z += cc[j] * v.z; acc.w += cc[j] * v.w;
        }
        acc.x += __shfl_xor(acc.x, 32, 64);
        acc.y += __shfl_xor(acc.y, 32, 64);
        acc.z += __shfl_xor(acc.z, 32, 64);
        acc.w += __shfl_xor(acc.w, 32, 64);
        if (lane < 32)
            *(float4*)&slab[wr * 4] = acc;
    }

    #pragma unroll 4
    for (int i = 0; i < 32; ++i) {
        const int r = i * 64 + lane;
        *(float4*)(right + (size_t)r * NDIM + c0) = *(float4*)&slab[r * 4];
    }
}

// ---------------------------------------------------------------------------
// post_scan: conv_hl(right -> Rh/Rl) [blocks 0..4095] merged with
// mw = right[inact] gather [blocks 4096..6143, half-row each].
// ---------------------------------------------------------------------------
__global__ __launch_bounds__(256) void post_scan(const float* __restrict__ right,
                                                 const int* __restrict__ inact,
                                                 unsigned short* __restrict__ Rh,
                                                 unsigned short* __restrict__ Rl,
                                                 float* __restrict__ mw)
{
    const int b = blockIdx.x;
    const int tid = threadIdx.x;
    if (b < 4096) {
        const long e = ((long)b * 256 + tid) * 4;
        float4 v = *(const float4*)(right + e);
        ushort4 hh, ll;
        split2(v.x, hh.x, ll.x); split2(v.y, hh.y, ll.y);
        split2(v.z, hh.z, ll.z); split2(v.w, hh.w, ll.w);
        *(ushort4*)(Rh + e) = hh;
        *(ushort4*)(Rl + e) = ll;
    } else {
        const int rb = b - 4096;
        const int r = rb >> 1;
        const int c = (rb & 1) * 1024 + tid * 4;
        *(float4*)(mw + (size_t)r * NDIM + c) =
            *(const float4*)(right + (size_t)inact[r] * NDIM + c);
    }
}

// ---------------------------------------------------------------------------
// Split-bf16 MFMA NT gemm with SPLIT-K (generic). 3-pass hi/lo, 128x128 tile,
// BK=32 (32KB LDS).
// R10: MFMA shape 16x16x32 -> 32x32x16 (2495 vs 2176 TF ubench; MFMA cycles
// per K-chunk 240 -> 192). Staging/barriers/grid UNCHANGED (same template).
// Fragment layouts: A/B row = lane&31, k = (lane>>5)*8 (extends the proven
// 16x16x32 pattern); C/D col=lane&31, row=(reg&3)+8*(reg>>2)+4*(lane>>5)
// (HW-verified, guide m74/m101). Wrong A/B layout would fail refcheck loudly.
// ---------------------------------------------------------------------------
#define GBK 32
__global__ __launch_bounds__(256) void mfma_nt(const unsigned short* __restrict__ Ah,
                                               const unsigned short* __restrict__ Al,
                                               const unsigned short* __restrict__ Bh,
                                               const unsigned short* __restrict__ Bl,
                                               float* __restrict__ C,
                                               long strideZ,
                                               int M, int N, int K, int ksplit)
{
    __shared__ unsigned short sA_h[4 * 128 * 8];   // 8 KB each, 32 KB total
    __shared__ unsigned short sA_l[4 * 128 * 8];
    __shared__ unsigned short sB_h[4 * 128 * 8];
    __shared__ unsigned short sB_l[4 * 128 * 8];

    const int tid  = threadIdx.x;
    const int wave = tid >> 6, lane = tid & 63;
    const int l31  = lane & 31;       // row/col within a 32-tile
    const int kh   = lane >> 5;       // k-half selector
    const int wm   = wave & 1,  wn   = wave >> 1;
    const int m0   = blockIdx.x * 128, n0 = blockIdx.y * 128;
    const int Kz   = K / ksplit;
    const int kbeg = Kz * blockIdx.z;
    C += (size_t)blockIdx.z * strideZ;

    const unsigned short* gbase;
    unsigned short* sbase;
    if      (wave == 0) { gbase = Ah + (size_t)m0 * K; sbase = sA_h; }
    else if (wave == 1) { gbase = Al + (size_t)m0 * K; sbase = sA_l; }
    else if (wave == 2) { gbase = Bh + (size_t)n0 * K; sbase = sB_h; }
    else                { gbase = Bl + (size_t)n0 * K; sbase = sB_l; }

    f32x16 acc[2][2];
    #pragma unroll
    for (int i = 0; i < 2; ++i)
        #pragma unroll
        for (int j = 0; j < 2; ++j)
            #pragma unroll
            for (int r = 0; r < 16; ++r) acc[i][j][r] = 0.f;

    for (int k0 = kbeg; k0 < kbeg + Kz; k0 += GBK) {
        #pragma unroll
        for (int h = 0; h < 2; ++h) {
            const unsigned short* gr = gbase + (size_t)(h * 64 + lane) * K + k0;
            unsigned short* sb = sbase + h * 512;
            #pragma unroll
            for (int c = 0; c < 4; ++c)
                gl2lds16(gr + c * 8, sb + c * 1024);
        }
        __syncthreads();
        #pragma unroll
        for (int t = 0; t < 2; ++t) {
            const int co = (t * 2 + kh) * 1024;
            bf16x8 ah[2], al[2], bh[2], bl[2];
            #pragma unroll
            for (int i = 0; i < 2; ++i) {
                const int m = wm * 64 + i * 32 + l31;
                ah[i] = *(const bf16x8*)&sA_h[co + m * 8];
                al[i] = *(const bf16x8*)&sA_l[co + m * 8];
            }
            #pragma unroll
            for (int j = 0; j < 2; ++j) {
                const int n = wn * 64 + j * 32 + l31;
                bh[j] = *(const bf16x8*)&sB_h[co + n * 8];
                bl[j] = *(const bf16x8*)&sB_l[co + n * 8];
            }
            #pragma unroll
            for (int i = 0; i < 2; ++i)
                #pragma unroll
                for (int j = 0; j < 2; ++j) {
                    acc[i][j] = __builtin_amdgcn_mfma_f32_32x32x16_bf16(ah[i], bh[j], acc[i][j], 0, 0, 0);
                    acc[i][j] = __builtin_amdgcn_mfma_f32_32x32x16_bf16(ah[i], bl[j], acc[i][j], 0, 0, 0);
                    acc[i][j] = __builtin_amdgcn_mfma_f32_32x32x16_bf16(al[i], bh[j], acc[i][j], 0, 0, 0);
                }
        }
        __syncthreads();
    }
    #pragma unroll
    for (int i = 0; i < 2; ++i) {
        const int rbase = m0 + wm * 64 + i * 32 + 4 * kh;
        #pragma unroll
        for (int j = 0; j < 2; ++j) {
            const int col = n0 + wn * 64 + j * 32 + l31;
            #pragma unroll
            for (int reg = 0; reg < 16; ++reg) {
                const int rrow = rbase + (reg & 3) + 8 * (reg >> 2);
                C[(size_t)rrow * N + col] = acc[i][j][reg];
            }
        }
    }
}

// ---------------------------------------------------------------------------
// mfma_daa_fused: Daa GEMM (Pa.F^T, M=N=HALF, K=NDIM, split-K=4, 256 blocks
// = 1 block/CU) with the RT = right^T tconv (1024 blocks) riding its shadow.
// GEMM path uses the same 32x32x16 scheme as mfma_nt (R10).
// ---------------------------------------------------------------------------
__global__ __launch_bounds__(256) void mfma_daa_fused(const unsigned short* __restrict__ Ah,
                                                      const unsigned short* __restrict__ Al,
                                                      const unsigned short* __restrict__ Bh,
                                                      const unsigned short* __restrict__ Bl,
                                                      float* __restrict__ C,
                                                      const float* __restrict__ right,
                                                      unsigned short* __restrict__ RTh,
                                                      unsigned short* __restrict__ RTl)
{
    __shared__ __align__(16) char smem[32768];
    const int tid = threadIdx.x;

    if (blockIdx.x >= 256) {
        // tconv: RT[k][m] = right[m][k], 64x64 tile, LDS-transposed.
        float* t = (float*)smem;   // [64][65]
        const int rb = blockIdx.x - 256;
        const int bi = rb & 31, bj = rb >> 5;
        const int tx = tid & 15, ty = tid >> 4;
        #pragma unroll
        for (int r = 0; r < 4; ++r) {
            const int row = bi * 64 + ty + r * 16;
            float4 v = *(const float4*)(right + (size_t)row * NDIM + bj * 64 + tx * 4);
            t[(ty + r * 16) * 65 + tx * 4 + 0] = v.x;
            t[(ty + r * 16) * 65 + tx * 4 + 1] = v.y;
            t[(ty + r * 16) * 65 + tx * 4 + 2] = v.z;
            t[(ty + r * 16) * 65 + tx * 4 + 3] = v.w;
        }
        __syncthreads();
        #pragma unroll
        for (int r = 0; r < 4; ++r) {
            const int drow = bj * 64 + ty + r * 16;
            ushort4 hh, ll;
            split2(t[(tx * 4 + 0) * 65 + ty + r * 16], hh.x, ll.x);
            split2(t[(tx * 4 + 1) * 65 + ty + r * 16], hh.y, ll.y);
            split2(t[(tx * 4 + 2) * 65 + ty + r * 16], hh.z, ll.z);
            split2(t[(tx * 4 + 3) * 65 + ty + r * 16], hh.w, ll.w);
            *(ushort4*)(RTh + (size_t)drow * NDIM + bi * 64 + tx * 4) = hh;
            *(ushort4*)(RTl + (size_t)drow * NDIM + bi * 64 + tx * 4) = ll;
        }
        return;
    }

    // GEMM path: M=N=HALF, K=NDIM, ksplit=4, strideZ=HALF*HALF.
    unsigned short* sA_h = (unsigned short*)smem;
    unsigned short* sA_l = sA_h + 4096;
    unsigned short* sB_h = sA_h + 8192;
    unsigned short* sB_l = sA_h + 12288;

    const int b = blockIdx.x;
    const int bx = b & 7, by = (b >> 3) & 7, bz = b >> 6;
    const int wave = tid >> 6, lane = tid & 63;
    const int l31  = lane & 31;
    const int kh   = lane >> 5;
    const int wm   = wave & 1,  wn   = wave >> 1;
    const int m0   = bx * 128, n0 = by * 128;
    const int Kz   = NDIM / 4;
    const int kbeg = Kz * bz;
    float* Cz = C + (size_t)bz * ((long)HALF * HALF);

    const unsigned short* gbase;
    unsigned short* sbase;
    if      (wave == 0) { gbase = Ah + (size_t)m0 * NDIM; sbase = sA_h; }
    else if (wave == 1) { gbase = Al + (size_t)m0 * NDIM; sbase = sA_l; }
    else if (wave == 2) { gbase = Bh + (size_t)n0 * NDIM; sbase = sB_h; }
    else                { gbase = Bl + (size_t)n0 * NDIM; sbase = sB_l; }

    f32x16 acc[2][2];
    #pragma unroll
    for (int i = 0; i < 2; ++i)
        #pragma unroll
        for (int j = 0; j < 2; ++j)
            #pragma unroll
            for (int r = 0; r < 16; ++r) acc[i][j][r] = 0.f;

    for (int k0 = kbeg; k0 < kbeg + Kz; k0 += GBK) {
        #pragma unroll
        for (int h = 0; h < 2; ++h) {
            const unsigned short* gr = gbase + (size_t)(h * 64 + lane) * NDIM + k0;
            unsigned short* sb = sbase + h * 512;
            #pragma unroll
            for (int c = 0; c < 4; ++c)
                gl2lds16(gr + c * 8, sb + c * 1024);
        }
        __syncthreads();
        #pragma unroll
        for (int t = 0; t < 2; ++t) {
            const int co = (t * 2 + kh) * 1024;
            bf16x8 ah[2], al[2], bh[2], bl[2];
            #pragma unroll
            for (int i = 0; i < 2; ++i) {
                const int m = wm * 64 + i * 32 + l31;
                ah[i] = *(const bf16x8*)&sA_h[co + m * 8];
                al[i] = *(const bf16x8*)&sA_l[co + m * 8];
            }
            #pragma unroll
            for (int j = 0; j < 2; ++j) {
                const int n = wn * 64 + j * 32 + l31;
                bh[j] = *(const bf16x8*)&sB_h[co + n * 8];
                bl[j] = *(const bf16x8*)&sB_l[co + n * 8];
            }
            #pragma unroll
            for (int i = 0; i < 2; ++i)
                #pragma unroll
                for (int j = 0; j < 2; ++j) {
                    acc[i][j] = __builtin_amdgcn_mfma_f32_32x32x16_bf16(ah[i], bh[j], acc[i][j], 0, 0, 0);
                    acc[i][j] = __builtin_amdgcn_mfma_f32_32x32x16_bf16(ah[i], bl[j], acc[i][j], 0, 0, 0);
                    acc[i][j] = __builtin_amdgcn_mfma_f32_32x32x16_bf16(al[i], bh[j], acc[i][j], 0, 0, 0);
                }
        }
        __syncthreads();
    }
    #pragma unroll
    for (int i = 0; i < 2; ++i) {
        const int rbase = m0 + wm * 64 + i * 32 + 4 * kh;
        #pragma unroll
        for (int j = 0; j < 2; ++j) {
            const int col = n0 + wn * 64 + j * 32 + l31;
            #pragma unroll
            for (int reg = 0; reg < 16; ++reg) {
                const int rrow = rbase + (reg & 3) + 8 * (reg >> 2);
                Cz[(size_t)rrow * HALF + col] = acc[i][j][reg];
            }
        }
    }
}

// ---------------------------------------------------------------------------
// reduce_k: dst[i] = sum_z parts[i + z*strideZ], float4 per thread.
// ---------------------------------------------------------------------------
__global__ __launch_bounds__(256) void reduce_k(float* __restrict__ dst,
                                                const float* __restrict__ parts,
                                                long strideZ, int nz, long n)
{
    const long i = ((long)blockIdx.x * 256 + threadIdx.x) * 4;
    if (i >= n) return;
    float4 s = *(const float4*)(parts + i);
    for (int z = 1; z < nz; ++z) {
        float4 v = *(const float4*)(parts + (size_t)z * strideZ + i);
        s.x += v.x; s.y += v.y; s.z += v.z; s.w += v.w;
    }
    *(float4*)(dst + i) = s;
}

// ---------------------------------------------------------------------------
// diag_step7: merged diag + step7 (validated R9).
//   blocks 0..2047:    diag_all[i] = dot(Pz0[i]+Pz1[i], right[i])
//   blocks 2048..4095: Pa = (Pz0+Pz1)[act] -> bf16 hi/lo
//   blocks 4096..6143: fw = right[act] (f32 + bf16 hi/lo), half-row each
// ---------------------------------------------------------------------------
__global__ __launch_bounds__(256) void diag_step7(const float* __restrict__ P0,
                                                  const float* __restrict__ P1,
                                                  const float* __restrict__ right,
                                                  const int* __restrict__ act,
                                                  float* __restrict__ diag_all,
                                                  float* __restrict__ fw,
                                                  unsigned short* __restrict__ Pah,
                                                  unsigned short* __restrict__ Pal,
                                                  unsigned short* __restrict__ Fh,
                                                  unsigned short* __restrict__ Fl)
{
    __shared__ float red[256];
    const int b = blockIdx.x;
    const int tid = threadIdx.x;

    if (b < 2048) {
        const int i = b;
        const float4* p4 = (const float4*)(P0 + (size_t)i * NDIM);
        const float4* q4 = (const float4*)(P1 + (size_t)i * NDIM);
        const float4* r4 = (const float4*)(right + (size_t)i * NDIM);
        float s = 0.f;
        for (int kq = tid; kq < NDIM / 4; kq += 256) {
            float4 a = p4[kq], b2 = r4[kq], a2 = q4[kq];
            a.x += a2.x; a.y += a2.y; a.z += a2.z; a.w += a2.w;
            s += a.x * b2.x + a.y * b2.y + a.z * b2.z + a.w * b2.w;
        }
        red[tid] = s;
        __syncthreads();
        for (int off = 128; off > 0; off >>= 1) {
            if (tid < off) red[tid] += red[tid + off];
            __syncthreads();
        }
        if (tid == 0) diag_all[i] = red[0];
        return;
    }
    if (b < 4096) {
        const int bb = b - 2048;
        const long e = ((long)bb * 256 + tid) * 4;
        const long row = e >> 11;
        const long col = e & (NDIM - 1);
        const long off = ((size_t)act[row] << 11) + col;
        float4 v = *(const float4*)(P0 + off);
        float4 v2 = *(const float4*)(P1 + off);
        v.x += v2.x; v.y += v2.y; v.z += v2.z; v.w += v2.w;
        ushort4 hh, ll;
        split2(v.x, hh.x, ll.x); split2(v.y, hh.y, ll.y);
        split2(v.z, hh.z, ll.z); split2(v.w, hh.w, ll.w);
        *(ushort4*)(Pah + e) = hh;
        *(ushort4*)(Pal + e) = ll;
        return;
    }
    {
        const int rb = b - 4096;          // 0..2047 -> r 0..1023
        const int r = rb >> 1;
        const int c = (rb & 1) * 1024 + tid * 4;
        const size_t e = (size_t)r * NDIM + c;
        float4 v = *(const float4*)(right + (size_t)act[r] * NDIM + c);
        *(float4*)(fw + e) = v;
        ushort4 hh, ll;
        split2(v.x, hh.x, ll.x); split2(v.y, hh.y, ll.y);
        split2(v.z, hh.z, ll.z); split2(v.w, hh.w, ll.w);
        *(ushort4*)(Fh + e) = hh;
        *(ushort4*)(Fl + e) = ll;
    }
}

// ---------------------------------------------------------------------------
// mid_kernel (validated R9): replaces reduce_k(fc) + step9 + prep2.
//   blocks 0..1023:   fc = sum of 4 Daa split-K partials; Dh/Dl = bf16(fc)
//   blocks 1024..1535: FT = fw^T tconv (grid 16x32)
//   block 1536:        prep2 (inva/dm/dmrow), 256 threads
// ---------------------------------------------------------------------------
__global__ __launch_bounds__(256) void mid_kernel(const float* __restrict__ parts,
                                                  const float* __restrict__ fw,
                                                  const int* __restrict__ act,
                                                  const int* __restrict__ inact,
                                                  const float* __restrict__ diag_all,
                                                  float* __restrict__ fc,
                                                  unsigned short* __restrict__ Dh,
                                                  unsigned short* __restrict__ Dl,
                                                  unsigned short* __restrict__ FTh,
                                                  unsigned short* __restrict__ FTl,
                                                  int* __restrict__ inva,
                                                  float* __restrict__ dm,
                                                  float* __restrict__ dmrow)
{
    __shared__ float t[64][65];
    const int b = blockIdx.x;
    const int tid = threadIdx.x;
    const long NH = (long)HALF * HALF;

    if (b < 1024) {
        const long i = ((long)b * 256 + tid) * 4;
        float4 s = *(const float4*)(parts + i);
        #pragma unroll
        for (int z = 1; z < 4; ++z) {
            float4 v = *(const float4*)(parts + (size_t)z * NH + i);
            s.x += v.x; s.y += v.y; s.z += v.z; s.w += v.w;
        }
        *(float4*)(fc + i) = s;
        ushort4 hh, ll;
        split2(s.x, hh.x, ll.x); split2(s.y, hh.y, ll.y);
        split2(s.z, hh.z, ll.z); split2(s.w, hh.w, ll.w);
        *(ushort4*)(Dh + i) = hh;
        *(ushort4*)(Dl + i) = ll;
        return;
    }
    if (b < 1536) {
        const int rb = b - 1024;          // tconv fw: Msrc=HALF, Ksrc=NDIM, 16x32
        const int bi = rb & 15, bj = rb >> 4;
        const int tx = tid & 15, ty = tid >> 4;
        #pragma unroll
        for (int r = 0; r < 4; ++r) {
            const int row = bi * 64 + ty + r * 16;
            float4 v = *(const float4*)(fw + (size_t)row * NDIM + bj * 64 + tx * 4);
            t[ty + r * 16][tx * 4 + 0] = v.x; t[ty + r * 16][tx * 4 + 1] = v.y;
            t[ty + r * 16][tx * 4 + 2] = v.z; t[ty + r * 16][tx * 4 + 3] = v.w;
        }
        __syncthreads();
        #pragma unroll
        for (int r = 0; r < 4; ++r) {
            const int drow = bj * 64 + ty + r * 16;
            ushort4 hh, ll;
            split2(t[tx * 4 + 0][ty + r * 16], hh.x, ll.x);
            split2(t[tx * 4 + 1][ty + r * 16], hh.y, ll.y);
            split2(t[tx * 4 + 2][ty + r * 16], hh.z, ll.z);
            split2(t[tx * 4 + 3][ty + r * 16], hh.w, ll.w);
            *(ushort4*)(FTh + (size_t)drow * HALF + bi * 64 + tx * 4) = hh;
            *(ushort4*)(FTl + (size_t)drow * HALF + bi * 64 + tx * 4) = ll;
        }
        return;
    }
    {
        for (int k = tid; k < 2048; k += 256) inva[k] = -1;
        __syncthreads();
        for (int k = tid; k < 1024; k += 256) {
            inva[act[k]] = k;
            const int ir = inact[k];
            const float dv = diag_all[ir];
            dm[k] = dv;
            dmrow[ir] = dv;
        }
    }
}

// ---------------------------------------------------------------------------
// GT[n,r] = Gfull[r,n] transposed+converted, Gfull fused on the fly.
// W1 comes as TWO split-K partials (W1a + W1b) — reduce fused in.
// ---------------------------------------------------------------------------
__global__ __launch_bounds__(256) void gt_build(const float* __restrict__ W1a,
                                                const float* __restrict__ W1b,
                                                const float* __restrict__ right,
                                                const int* __restrict__ inva,
                                                const float* __restrict__ dmrow,
                                                unsigned short* __restrict__ h,
                                                unsigned short* __restrict__ l)
{
    __shared__ float t[64][65];
    const int bi = blockIdx.x, bj = blockIdx.y;
    const int tx = threadIdx.x & 15, ty = threadIdx.x >> 4;
    #pragma unroll
    for (int rr = 0; rr < 4; ++rr) {
        const int r = bi * 64 + ty + rr * 16;
        const int ia = inva[r];
        float4 v;
        if (ia >= 0) {
            const size_t o = (size_t)ia * NDIM + bj * 64 + tx * 4;
            v = *(const float4*)(W1a + o);
            float4 v2 = *(const float4*)(W1b + o);
            v.x += v2.x; v.y += v2.y; v.z += v2.z; v.w += v2.w;
        } else {
            v = *(const float4*)(right + (size_t)r * NDIM + bj * 64 + tx * 4);
            const float s = dmrow[r];
            v.x *= s; v.y *= s; v.z *= s; v.w *= s;
        }
        t[ty + rr * 16][tx * 4 + 0] = v.x; t[ty + rr * 16][tx * 4 + 1] = v.y;
        t[ty + rr * 16][tx * 4 + 2] = v.z; t[ty + rr * 16][tx * 4 + 3] = v.w;
    }
    __syncthreads();
    #pragma unroll
    for (int rr = 0; rr < 4; ++rr) {
        const int drow = bj * 64 + ty + rr * 16;
        ushort4 hh, ll;
        split2(t[tx * 4 + 0][ty + rr * 16], hh.x, ll.x);
        split2(t[tx * 4 + 1][ty + rr * 16], hh.y, ll.y);
        split2(t[tx * 4 + 2][ty + rr * 16], hh.z, ll.z);
        split2(t[tx * 4 + 3][ty + rr * 16], hh.w, ll.w);
        *(ushort4*)(h + (size_t)drow * NDIM + bi * 64 + tx * 4) = hh;
        *(ushort4*)(l + (size_t)drow * NDIM + bi * 64 + tx * 4) = ll;
    }
}

// tail_kernel: build_D [blocks 0..16383] + mc = diag(dm) [blocks 16384..20479].
__global__ __launch_bounds__(256) void tail_kernel(const float* __restrict__ Daa,
                                                   const float* __restrict__ diag_all,
                                                   const int* __restrict__ inva,
                                                   const float* __restrict__ dm,
                                                   float* __restrict__ D,
                                                   float* __restrict__ mc)
{
    const int b = blockIdx.x;
    if (b < 16384) {
        const int e = b * 256 + threadIdx.x;
        const int i = e >> 11, j = e & (NDIM - 1);
        const int ii = inva[i], jj = inva[j];
        float v = 0.f;
        if (ii >= 0 && jj >= 0) v = Daa[ii * HALF + jj];
        if (i == j) v = diag_all[i];
        D[e] = v;
    } else {
        const int e = (b - 16384) * 256 + threadIdx.x;
        const int t = e >> 10, s = e & (HALF - 1);
        mc[e] = (t == s) ? dm[t] : 0.f;
    }
}

// ---------------------------------------------------------------------------
// Fallback-path helpers (fp32 path only)
// ---------------------------------------------------------------------------
__global__ __launch_bounds__(256) void diag_kernel(const float* __restrict__ P,
                                                   const float* __restrict__ P2,
                                                   const float* __restrict__ R,
                                                   float* __restrict__ diag_all)
{
    __shared__ float red[256];
    const int i = blockIdx.x;
    const float4* p4 = (const float4*)(P + (size_t)i * NDIM);
    const float4* q4 = P2 ? (const float4*)(P2 + (size_t)i * NDIM) : nullptr;
    const float4* r4 = (const float4*)(R + (size_t)i * NDIM);
    float s = 0.f;
    for (int kq = threadIdx.x; kq < NDIM / 4; kq += 256) {
        float4 a = p4[kq], b = r4[kq];
        if (q4) {
            float4 a2 = q4[kq];
            a.x += a2.x; a.y += a2.y; a.z += a2.z; a.w += a2.w;
        }
        s += a.x * b.x + a.y * b.y + a.z * b.z + a.w * b.w;
    }
    red[threadIdx.x] = s;
    __syncthreads();
    for (int off = 128; off > 0; off >>= 1) {
        if (threadIdx.x < off) red[threadIdx.x] += red[threadIdx.x + off];
        __syncthreads();
    }
    if (threadIdx.x == 0) diag_all[i] = red[0];
}

__global__ void prep2_kernel(const int* __restrict__ act, const int* __restrict__ inact,
                             const float* __restrict__ diag_all,
                             int* __restrict__ inva, float* __restrict__ dm,
                             float* __restrict__ dmrow)
{
    const int t = threadIdx.x;
    inva[t] = -1;
    inva[t + HALF] = -1;
    __syncthreads();
    inva[act[t]] = t;
    const int ir = inact[t];
    const float dv = diag_all[ir];
    dm[t] = dv;
    dmrow[ir] = dv;
}

__global__ __launch_bounds__(512) void gather_rows(const float* __restrict__ R,
                                                   const int* __restrict__ ridx,
                                                   float* __restrict__ outp)
{
    const int r = blockIdx.x;
    const int c = threadIdx.x * 4;
    *(float4*)(outp + (size_t)r * NDIM + c) =
        *(const float4*)(R + (size_t)ridx[r] * NDIM + c);
}

__global__ __launch_bounds__(64) void scan_kernel(const float* __restrict__ O,
                                                  const int* __restrict__ idx,
                                                  float* __restrict__ right)
{
    __shared__ float slab[NDIM * 8];
    const int lane = threadIdx.x;
    const int c0 = blockIdx.x * 8;
    const int k  = lane >> 2;
    const int c2 = (lane & 3) * 2;

    for (int r = lane; r < NDIM; r += 64) {
        *(float4*)&slab[r * 8]     = make_float4(0.f, 0.f, 0.f, 0.f);
        *(float4*)&slab[r * 8 + 4] = make_float4(0.f, 0.f, 0.f, 0.f);
    }
    if (lane < 8) slab[(c0 + lane) * 8 + lane] = 1.0f;

    int rows[16]; float a[16]; int wrow;
    #pragma unroll
    for (int j = 0; j < 16; ++j) rows[j] = idx[j];
    {
        const float4* p4 = (const float4*)(O + k * 16);
        #pragma unroll
        for (int q = 0; q < 4; ++q) *(float4*)&a[q * 4] = p4[q];
    }
    wrow = idx[k];

    for (int l = 0; l < LLEV; ++l) {
        int rr[16]; float aa[16];
        const int wr = wrow;
        #pragma unroll
        for (int j = 0; j < 16; ++j) { rr[j] = rows[j]; aa[j] = a[j]; }
        if (l + 1 < LLEV) {
            const int* ip = idx + (l + 1) * 16;
            #pragma unroll
            for (int j = 0; j < 16; ++j) rows[j] = ip[j];
            const float4* p4 = (const float4*)(O + (l + 1) * 256 + k * 16);
            #pragma unroll
            for (int q = 0; q < 4; ++q) *(float4*)&a[q * 4] = p4[q];
            wrow = ip[k];
        }
        float sx = 0.f, sy = 0.f;
        #pragma unroll
        for (int j = 0; j < 16; ++j) {
            float2 v = *(float2*)&slab[rr[j] * 8 + c2];
            sx += aa[j] * v.x;
            sy += aa[j] * v.y;
        }
        *(float2*)&slab[wr * 8 + c2] = make_float2(sx, sy);
    }

    for (int r0 = 0; r0 < NDIM; r0 += 32) {
        const int r = r0 + (lane >> 1);
        const int h = (lane & 1) * 4;
        *(float4*)(right + (size_t)r * NDIM + c0 + h) = *(float4*)&slab[r * 8 + h];
    }
}

__global__ __launch_bounds__(256) void gemm_nt64(const float* __restrict__ A, int lda,
                                                 const int* __restrict__ ridxA,
                                                 const float* __restrict__ B, int ldb,
                                                 const int* __restrict__ ridxB,
                                                 float* __restrict__ C, int ldc, int Kk)
{
    __shared__ float As[16][68];
    __shared__ float Bs[16][68];
    const int tid = threadIdx.x;
    const int tx = tid & 15, ty = tid >> 4;
    const int m0 = blockIdx.x * 64, n0 = blockIdx.y * 64;
    const int li = tid >> 2;
    const int lk = (tid & 3) * 4;
    int rowA = m0 + li; if (ridxA) rowA = ridxA[rowA];
    int rowB = n0 + li; if (ridxB) rowB = ridxB[rowB];
    const float* pA = A + (size_t)rowA * lda + lk;
    const float* pB = B + (size_t)rowB * ldb + lk;
    float acc[4][4] = {};
    for (int k0 = 0; k0 < Kk; k0 += 16) {
        float4 a4 = *(const float4*)(pA + k0);
        float4 b4 = *(const float4*)(pB + k0);
        As[lk + 0][li] = a4.x; As[lk + 1][li] = a4.y; As[lk + 2][li] = a4.z; As[lk + 3][li] = a4.w;
        Bs[lk + 0][li] = b4.x; Bs[lk + 1][li] = b4.y; Bs[lk + 2][li] = b4.z; Bs[lk + 3][li] = b4.w;
        __syncthreads();
        #pragma unroll
        for (int kk = 0; kk < 16; ++kk) {
            float4 av = *(const float4*)&As[kk][ty * 4];
            float4 bv = *(const float4*)&Bs[kk][tx * 4];
            float a[4] = {av.x, av.y, av.z, av.w};
            float b[4] = {bv.x, bv.y, bv.z, bv.w};
            #pragma unroll
            for (int i = 0; i < 4; ++i)
                #pragma unroll
                for (int j = 0; j < 4; ++j) acc[i][j] += a[i] * b[j];
        }
        __syncthreads();
    }
    #pragma unroll
    for (int i = 0; i < 4; ++i) {
        float4 v = make_float4(acc[i][0], acc[i][1], acc[i][2], acc[i][3]);
        *(float4*)(C + (size_t)(m0 + ty * 4 + i) * ldc + n0 + tx * 4) = v;
    }
}

__global__ __launch_bounds__(256) void gemm_nn64(const float* __restrict__ A, int lda,
                                                 const float* __restrict__ B, int ldb,
                                                 float* __restrict__ C, int ldc, int Kk)
{
    __shared__ float As[16][68];
    __shared__ float Bs[16][68];
    const int tid = threadIdx.x;
    const int tx = tid & 15, ty = tid >> 4;
    const int m0 = blockIdx.x * 64, n0 = blockIdx.y * 64;
    const int li = tid >> 2;
    const int lk = (tid & 3) * 4;
    const int bk = tid >> 4;
    const int bn = (tid & 15) * 4;
    const float* pA = A + (size_t)(m0 + li) * lda + lk;
    float acc[4][4] = {};
    for (int k0 = 0; k0 < Kk; k0 += 16) {
        float4 a4 = *(const float4*)(pA + k0);
        float4 b4 = *(const float4*)(B + (size_t)(k0 + bk) * ldb + n0 + bn);
        As[lk + 0][li] = a4.x; As[lk + 1][li] = a4.y; As[lk + 2][li] = a4.z; As[lk + 3][li] = a4.w;
        *(float4*)&Bs[bk][bn] = b4;
        __syncthreads();
        #pragma unroll
        for (int kk = 0; kk < 16; ++kk) {
            float4 av = *(const float4*)&As[kk][ty * 4];
            float4 bv = *(const float4*)&Bs[kk][tx * 4];
            float a[4] = {av.x, av.y, av.z, av.w};
            float b[4] = {bv.x, bv.y, bv.z, bv.w};
            #pragma unroll
            for (int i = 0; i < 4; ++i)
                #pragma unroll
                for (int j = 0; j < 4; ++j) acc[i][j] += a[i] * b[j];
        }
        __syncthreads();
    }
    #pragma unroll
    for (int i = 0; i < 4; ++i) {
        float4 v = make_float4(acc[i][0], acc[i][1], acc[i][2], acc[i][3]);
        *(float4*)(C + (size_t)(m0 + ty * 4 + i) * ldc + n0 + tx * 4) = v;
    }
}

__global__ __launch_bounds__(256) void arec64(const float* __restrict__ fw,
                                              const float* __restrict__ mw,
                                              const float* __restrict__ W1,
                                              const float* __restrict__ dm,
                                              float* __restrict__ C)
{
    __shared__ float As[16][68];
    __shared__ float Bs[16][68];
    const int tid = threadIdx.x;
    const int tx = tid & 15, ty = tid >> 4;
    const int m0 = blockIdx.x * 64, n0 = blockIdx.y * 64;
    const int bk = tid >> 4;
    const int bn = (tid & 15) * 4;
    float acc[4][4] = {};
    for (int t0 = 0; t0 < NDIM; t0 += 16) {
        const int t = t0 + bk;
        const float* Hrow; const float* Grow; float gs;
        if (t < HALF) { Hrow = fw + (size_t)t * NDIM; Grow = W1 + (size_t)t * NDIM; gs = 1.f; }
        else          { Hrow = mw + (size_t)(t - HALF) * NDIM; Grow = Hrow; gs = dm[t - HALF]; }
        float4 a4 = *(const float4*)(Hrow + m0 + bn);
        float4 b4 = *(const float4*)(Grow + n0 + bn);
        b4.x *= gs; b4.y *= gs; b4.z *= gs; b4.w *= gs;
        *(float4*)&As[bk][bn] = a4;
        *(float4*)&Bs[bk][bn] = b4;
        __syncthreads();
        #pragma unroll
        for (int kk = 0; kk < 16; ++kk) {
            float4 av = *(const float4*)&As[kk][ty * 4];
            float4 bv = *(const float4*)&Bs[kk][tx * 4];
            float a[4] = {av.x, av.y, av.z, av.w};
            float b[4] = {bv.x, bv.y, bv.z, bv.w};
            #pragma unroll
            for (int i = 0; i < 4; ++i)
                #pragma unroll
                for (int j = 0; j < 4; ++j) acc[i][j] += a[i] * b[j];
        }
        __syncthreads();
    }
    #pragma unroll
    for (int i = 0; i < 4; ++i) {
        float4 v = make_float4(acc[i][0], acc[i][1], acc[i][2], acc[i][3]);
        *(float4*)(C + (size_t)(m0 + ty * 4 + i) * NDIM + n0 + tx * 4) = v;
    }
}

__global__ __launch_bounds__(256) void build_D(const float* __restrict__ Daa,
                                               const float* __restrict__ diag_all,
                                               const int* __restrict__ inva,
                                               float* __restrict__ D)
{
    const int e = blockIdx.x * 256 + threadIdx.x;
    const int i = e >> 11, j = e & (NDIM - 1);
    const int ii = inva[i], jj = inva[j];
    float v = 0.f;
    if (ii >= 0 && jj >= 0) v = Daa[ii * HALF + jj];
    if (i == j) v = diag_all[i];
    D[e] = v;
}

__global__ __launch_bounds__(256) void mc_kernel(const float* __restrict__ dm,
                                                 float* __restrict__ mc)
{
    const int e = blockIdx.x * 256 + threadIdx.x;
    const int t = e >> 10, s = e & (HALF - 1);
    mc[e] = (t == s) ? dm[t] : 0.f;
}

// ---------------------------------------------------------------------------
extern "C" void kernel_launch(void* const* d_in, const int* in_sizes, int n_in,
                              void* d_out, int out_size, void* d_ws, size_t ws_size,
                              hipStream_t stream)
{
    (void)in_sizes; (void)n_in; (void)out_size;
    const float* A     = (const float*)d_in[0];
    const float* O     = (const float*)d_in[1];
    const int*   idx   = (const int*)d_in[2];
    const int*   act   = (const int*)d_in[3];
    const int*   inact = (const int*)d_in[4];

    float* out = (float*)d_out;
    const size_t NN = (size_t)NDIM * NDIM;
    float* A_rec = out;                       // scratch for P(z0) until final gemm
    float* right = out + NN;
    float* D     = out + 2 * NN;              // scratch: split-K partials / W1
    float* mc    = out + 3 * NN;
    float* fc    = mc + (size_t)HALF * HALF;  // Daa
    float* mw    = fc + (size_t)HALF * HALF;
    float* fw    = mw + (size_t)HALF * NDIM;

    char*  w        = (char*)d_ws;
    float* diag_all = (float*)w;              // 2048 f
    float* dm       = (float*)(w + 8192);     // 1024 f
    int*   inva     = (int*)(w + 12288);      // 2048 i
    float* dmrow    = (float*)(w + 20480);    // 2048 f

    const size_t MB = 1024 * 1024;
    const size_t WS_NEEDED = 65536 + 32 * MB;

    if (ws_size >= WS_NEEDED) {
        char* r1 = w + 65536;                 // 16 MB: (Warr/Sarr) -> Rh/Rl -> RTh/RTl
        char* r2 = r1 + 16 * MB;              // 16 MB: Ah/Al -> Pa/F -> D/FT -> GT
        float* Warr = (float*)r1;             // 1 MB (consumed by scan3)
        int*   Sarr = (int*)(r1 + MB);        // 32 KB
        unsigned short* Rh  = (unsigned short*)r1;
        unsigned short* Rl  = (unsigned short*)(r1 + 8 * MB);
        unsigned short* RTh = Rh;
        unsigned short* RTl = Rl;
        unsigned short* Ah  = (unsigned short*)r2;
        unsigned short* Al  = (unsigned short*)(r2 + 8 * MB);
        unsigned short* Pah = (unsigned short*)r2;             // after P
        unsigned short* Pal = (unsigned short*)(r2 + 4 * MB);
        unsigned short* Fh  = (unsigned short*)(r2 + 8 * MB);
        unsigned short* Fl  = (unsigned short*)(r2 + 12 * MB);
        unsigned short* Dh  = (unsigned short*)r2;             // after Daa
        unsigned short* Dl  = (unsigned short*)(r2 + 2 * MB);
        unsigned short* FTh = (unsigned short*)(r2 + 4 * MB);
        unsigned short* FTl = (unsigned short*)(r2 + 8 * MB);
        unsigned short* GTh = (unsigned short*)r2;             // after W1
        unsigned short* GTl = (unsigned short*)(r2 + 8 * MB);

        // 1. compose; scan with conv_hl(A) in its shadow
        compose_kernel<<<256, 64, 0, stream>>>(O, idx, Sarr, Warr);
        scan3_fused<<<512 + 8192, 64, 0, stream>>>(Warr, Sarr, right, A, Ah, Al);
        // 2. conv right->Rh/Rl + gather mw (merged)
        post_scan<<<6144, 256, 0, stream>>>(right, inact, Rh, Rl, mw);
        // 3. P = R @ A, split-K=2: z0 -> A_rec, z1 -> D slot
        mfma_nt<<<dim3(16, 16, 2), 256, 0, stream>>>(Rh, Rl, Ah, Al, A_rec,
                                                     (long)2 * NN, NDIM, NDIM, NDIM, 2);
        // 4. diag + Pa conv + fw gather/conv (merged)
        diag_step7<<<6144, 256, 0, stream>>>(A_rec, A_rec + 2 * NN, right, act,
                                             diag_all, fw, Pah, Pal, Fh, Fl);
        // 5. Daa GEMM (1 block/CU) with RT = right^T tconv riding its shadow
        mfma_daa_fused<<<256 + 1024, 256, 0, stream>>>(Pah, Pal, Fh, Fl, D,
                                                       right, RTh, RTl);
        // 6. fc = sum partials (+bf16 conv fused) + FT tconv + prep2 (merged)
        mid_kernel<<<1537, 256, 0, stream>>>(D, fw, act, inact, diag_all,
                                             fc, Dh, Dl, FTh, FTl,
                                             inva, dm, dmrow);
        // 7. W1 = Daa @ fw, split-K=2 (partials summed inline by gt_build)
        mfma_nt<<<dim3(8, 16, 2), 256, 0, stream>>>(Dh, Dl, FTh, FTl, D,
                                                    (long)HALF * NDIM, HALF, NDIM, HALF, 2);
        // 8. GT from (W1z0+W1z1) / dm*right
        gt_build<<<dim3(32, 32), 256, 0, stream>>>(D, D + (size_t)HALF * NDIM,
                                                   right, inva, dmrow, GTh, GTl);
        // 9. A_rec = RT . GT^T, split-K=2; reduce (output must materialize)
        mfma_nt<<<dim3(16, 16, 2), 256, 0, stream>>>(RTh, RTl, GTh, GTl, A_rec,
                                                     (long)2 * NN, NDIM, NDIM, NDIM, 2);
        reduce_k<<<4096, 256, 0, stream>>>(A_rec, A_rec, (long)2 * NN, 2, (long)NN);
        // 10. D output + mc (merged)
        tail_kernel<<<20480, 256, 0, stream>>>(fc, diag_all, inva, dm, D, mc);
    } else {
        // fp32 fallback (R1 structure)
        scan_kernel<<<256, 64, 0, stream>>>(O, idx, right);
        gather_rows<<<1024, 512, 0, stream>>>(right, act, fw);
        gather_rows<<<1024, 512, 0, stream>>>(right, inact, mw);
        gemm_nt64<<<dim3(32, 32), 256, 0, stream>>>(right, NDIM, nullptr, A, NDIM, nullptr,
                                                    A_rec, NDIM, NDIM);
        diag_kernel<<<2048, 256, 0, stream>>>(A_rec, nullptr, right, diag_all);
        prep2_kernel<<<1, 1024, 0, stream>>>(act, inact, diag_all, inva, dm, dmrow);
        gemm_nt64<<<dim3(16, 16), 256, 0, stream>>>(A_rec, NDIM, act, right, NDIM, act,
                                                    fc, HALF, NDIM);
        gemm_nn64<<<dim3(16, 32), 256, 0, stream>>>(fc, HALF, fw, NDIM, D, NDIM, HALF);
        arec64<<<dim3(32, 32), 256, 0, stream>>>(fw, mw, D, dm, A_rec);
        build_D<<<16384, 256, 0, stream>>>(fc, diag_all, inva, D);
        mc_kernel<<<4096, 256, 0, stream>>>(dm, mc);
    }
}